// Round 1
// baseline (511.417 us; speedup 1.0000x reference)
//
#include <hip/hip_runtime.h>
#include <hip/hip_bf16.h>
#include <math.h>

#define N_NODES 50000
#define N_EDGES 500000
#define FC_BLOCKS 1024

// ---------------------------------------------------------------------------
// CSR build
// ---------------------------------------------------------------------------
__global__ void hist_kernel(const int* __restrict__ dst, int* __restrict__ cnt) {
  int e = blockIdx.x * blockDim.x + threadIdx.x;
  if (e < N_EDGES) atomicAdd(&cnt[dst[e]], 1);
}

__global__ void chunk_sum_kernel(const int* __restrict__ cnt, int* __restrict__ bsum) {
  __shared__ int s[512];
  int i = blockIdx.x * 512 + threadIdx.x;
  s[threadIdx.x] = (i < N_NODES) ? cnt[i] : 0;
  __syncthreads();
  for (int off = 256; off > 0; off >>= 1) {
    if (threadIdx.x < off) s[threadIdx.x] += s[threadIdx.x + off];
    __syncthreads();
  }
  if (threadIdx.x == 0) bsum[blockIdx.x] = s[0];
}

__global__ void scan_bsum_kernel(int* __restrict__ bsum, int n) {
  if (blockIdx.x == 0 && threadIdx.x == 0) {
    int acc = 0;
    for (int i = 0; i < n; i++) { int v = bsum[i]; bsum[i] = acc; acc += v; }
  }
}

__global__ void scan_final_kernel(const int* __restrict__ cnt, const int* __restrict__ bsum,
                                  int* __restrict__ row_ptr, float* __restrict__ inv_deg) {
  __shared__ int s[512];
  int i = blockIdx.x * 512 + threadIdx.x;
  int v = (i < N_NODES) ? cnt[i] : 0;
  s[threadIdx.x] = v;
  __syncthreads();
  for (int off = 1; off < 512; off <<= 1) {
    int t = (threadIdx.x >= off) ? s[threadIdx.x - off] : 0;
    __syncthreads();
    s[threadIdx.x] += t;
    __syncthreads();
  }
  if (i < N_NODES) {
    row_ptr[i + 1] = bsum[blockIdx.x] + s[threadIdx.x];
    if (i == 0) row_ptr[0] = 0;
    inv_deg[i] = 1.0f / fmaxf((float)v, 1.0f);
  }
}

__global__ void fill_csr_kernel(const int* __restrict__ src, const int* __restrict__ dst,
                                const int* __restrict__ row_ptr, int* __restrict__ fill,
                                int* __restrict__ col) {
  int e = blockIdx.x * blockDim.x + threadIdx.x;
  if (e < N_EDGES) {
    int d = dst[e];
    int pos = row_ptr[d] + atomicAdd(&fill[d], 1);
    col[pos] = src[e];
  }
}

// ---------------------------------------------------------------------------
// Weight packing: Wt[k][j] layouts (transposed, concatenated)
// ---------------------------------------------------------------------------
__global__ void pack_kcat_kernel(const float* __restrict__ Wl, const float* __restrict__ Wr,
                                 float* __restrict__ Wt, int FIl, int FIr, int FO) {
  int idx = blockIdx.x * 256 + threadIdx.x;
  int FI = FIl + FIr;
  if (idx < FI * FO) {
    int k = idx / FO, j = idx % FO;
    Wt[idx] = (k < FIl) ? Wl[j * FIl + k] : Wr[j * FIr + (k - FIl)];
  }
}

__global__ void pack_jcat_kernel(const float* __restrict__ Wl, const float* __restrict__ Wr,
                                 float* __restrict__ Wt, int FI, int FOh) {
  int idx = blockIdx.x * 256 + threadIdx.x;
  int FO = 2 * FOh;
  if (idx < FI * FO) {
    int k = idx / FO, j = idx % FO;
    Wt[idx] = (j < FOh) ? Wl[j * FI + k] : Wr[(j - FOh) * FI + k];
  }
}

// ---------------------------------------------------------------------------
// Aggregation kernels (gather over CSR)
// ---------------------------------------------------------------------------
template<int F>
__global__ void agg_mean_kernel(const float* __restrict__ xin, const int* __restrict__ row_ptr,
                                const int* __restrict__ col, const float* __restrict__ inv_deg,
                                float* __restrict__ out) {
  int node = blockIdx.x;
  int f = threadIdx.x;
  int beg = row_ptr[node], end = row_ptr[node + 1];
  float acc = 0.f;
  for (int e = beg; e < end; e++) acc += xin[(size_t)col[e] * F + f];
  out[(size_t)node * F + f] = acc * inv_deg[node];
}

// out = relu(l2norm( agg(yl)/deg + bias + yr_row ))
template<int F>
__global__ void agg_norm_relu_kernel(const float* __restrict__ yl, const float* __restrict__ yr,
                                     const float* __restrict__ bias, const int* __restrict__ row_ptr,
                                     const int* __restrict__ col, const float* __restrict__ inv_deg,
                                     float* __restrict__ out) {
  __shared__ float wsum[2];
  int node = blockIdx.x;
  int f = threadIdx.x;
  int beg = row_ptr[node], end = row_ptr[node + 1];
  float acc = 0.f;
  for (int e = beg; e < end; e++) acc += yl[(size_t)col[e] * F + f];
  float v = acc * inv_deg[node] + bias[f] + yr[(size_t)node * F + f];
  float p = v * v;
  #pragma unroll
  for (int msk = 1; msk <= 32; msk <<= 1) p += __shfl_xor(p, msk);
  float tot;
  if (F == 128) {
    if ((f & 63) == 0) wsum[f >> 6] = p;
    __syncthreads();
    tot = wsum[0] + wsum[1];
  } else {
    tot = p;
  }
  float sc = 1.0f / fmaxf(sqrtf(tot), 1e-12f);
  out[(size_t)node * F + f] = fmaxf(v * sc, 0.f);
}

// ---------------------------------------------------------------------------
// GEMM: out[N,FO] = A[N,FI] @ Wt  (Wt packed [FI][FO])
// ASPLIT: A columns k<FI1 from A1, else A2 (both row-stride FI1 / FI-FI1)
// POST: add bias, L2-normalize over FO, relu (single-plane output, stride FO)
// OSPLIT: write cols [0,FO/2) to outA, [FO/2,FO) to outB (stride FO/2 each)
// ---------------------------------------------------------------------------
template<int FI, int FO, bool ASPLIT, int FI1, bool POST, bool OSPLIT>
__launch_bounds__(256)
__global__ void gemm_kernel(const float* __restrict__ A1, const float* __restrict__ A2,
                            const float* __restrict__ Wt, const float* __restrict__ bias,
                            float* __restrict__ outA, float* __restrict__ outB) {
  constexpr int KT = 32, TM = 32;
  constexpr int JT = FO / 32;   // cols per thread
  constexpr int JV = JT / 4;    // float4s per thread
  __shared__ float Ws[KT][FO];
  __shared__ float As[TM][KT];
  const int tid = threadIdx.x;
  const int tj = tid & 31;
  const int tm = tid >> 5;
  const int node0 = blockIdx.x * TM;

  float acc[4][JT];
  #pragma unroll
  for (int mi = 0; mi < 4; mi++)
    #pragma unroll
    for (int jj = 0; jj < JT; jj++) acc[mi][jj] = 0.f;

  for (int k0 = 0; k0 < FI; k0 += KT) {
    // stage W tile (contiguous copy, coalesced, conflict-free)
    const float4* wsrc = (const float4*)(Wt + (size_t)k0 * FO);
    float4* wdst = (float4*)(&Ws[0][0]);
    for (int i = tid; i < KT * FO / 4; i += 256) wdst[i] = wsrc[i];
    // stage A tile [32 rows][32 k]
    {
      const float* src = A1; int kof = k0; int astr = ASPLIT ? FI1 : FI;
      if (ASPLIT && k0 >= FI1) { src = A2; kof = k0 - FI1; astr = FI - FI1; }
      int m = tid >> 3;
      int c4 = (tid & 7) * 4;
      int row = node0 + m; if (row >= N_NODES) row = N_NODES - 1;
      *(float4*)&As[m][c4] = *(const float4*)&src[(size_t)row * astr + kof + c4];
    }
    __syncthreads();
    #pragma unroll
    for (int kk = 0; kk < KT; kk += 4) {
      float4 a[4];
      #pragma unroll
      for (int mi = 0; mi < 4; mi++) a[mi] = *(const float4*)&As[tm * 4 + mi][kk];
      #pragma unroll
      for (int u = 0; u < 4; u++) {
        float w[JT];
        #pragma unroll
        for (int jv = 0; jv < JV; jv++) {
          float4 wv = *(const float4*)&Ws[kk + u][tj * JT + jv * 4];
          w[jv * 4 + 0] = wv.x; w[jv * 4 + 1] = wv.y;
          w[jv * 4 + 2] = wv.z; w[jv * 4 + 3] = wv.w;
        }
        #pragma unroll
        for (int mi = 0; mi < 4; mi++) {
          float av = ((const float*)&a[mi])[u];
          #pragma unroll
          for (int jj = 0; jj < JT; jj++) acc[mi][jj] = fmaf(av, w[jj], acc[mi][jj]);
        }
      }
    }
    __syncthreads();
  }

  if (POST) {
    float bj[JT];
    #pragma unroll
    for (int jj = 0; jj < JT; jj++) bj[jj] = bias[tj * JT + jj];
    float p[4] = {0.f, 0.f, 0.f, 0.f};
    #pragma unroll
    for (int mi = 0; mi < 4; mi++)
      #pragma unroll
      for (int jj = 0; jj < JT; jj++) {
        float v = acc[mi][jj] + bj[jj];
        acc[mi][jj] = v;
        p[mi] += v * v;
      }
    // reduce over the 32 lanes (tj) within each half-wave (fixed tm)
    #pragma unroll
    for (int msk = 1; msk <= 16; msk <<= 1)
      #pragma unroll
      for (int mi = 0; mi < 4; mi++) p[mi] += __shfl_xor(p[mi], msk);
    #pragma unroll
    for (int mi = 0; mi < 4; mi++) {
      float sc = 1.0f / fmaxf(sqrtf(p[mi]), 1e-12f);
      #pragma unroll
      for (int jj = 0; jj < JT; jj++) acc[mi][jj] = fmaxf(acc[mi][jj] * sc, 0.f);
    }
  }

  #pragma unroll
  for (int mi = 0; mi < 4; mi++) {
    int row = node0 + tm * 4 + mi;
    if (row < N_NODES) {
      #pragma unroll
      for (int jv = 0; jv < JV; jv++) {
        int j = tj * JT + jv * 4;
        float4 o = make_float4(acc[mi][jv * 4 + 0], acc[mi][jv * 4 + 1],
                               acc[mi][jv * 4 + 2], acc[mi][jv * 4 + 3]);
        if (!OSPLIT) {
          *(float4*)&outA[(size_t)row * FO + j] = o;
        } else {
          if (j < FO / 2) *(float4*)&outA[(size_t)row * (FO / 2) + j] = o;
          else            *(float4*)&outB[(size_t)row * (FO / 2) + (j - FO / 2)] = o;
        }
      }
    }
  }
}

// ---------------------------------------------------------------------------
// FC: logits = fcW @ h3.flat + fcb; softmax
// ---------------------------------------------------------------------------
__global__ void fc_partial_kernel(const float* __restrict__ fcW, const float* __restrict__ h3,
                                  float* __restrict__ partial) {
  const size_t L = (size_t)N_NODES * 64;
  float acc[5] = {0.f, 0.f, 0.f, 0.f, 0.f};
  for (size_t i = (size_t)blockIdx.x * 256 + threadIdx.x; i < L; i += (size_t)gridDim.x * 256) {
    float h = h3[i];
    #pragma unroll
    for (int c = 0; c < 5; c++) acc[c] += h * fcW[(size_t)c * L + i];
  }
  __shared__ float red[4][5];
  #pragma unroll
  for (int msk = 1; msk <= 32; msk <<= 1)
    #pragma unroll
    for (int c = 0; c < 5; c++) acc[c] += __shfl_xor(acc[c], msk);
  int lane = threadIdx.x & 63, wave = threadIdx.x >> 6;
  if (lane == 0)
    #pragma unroll
    for (int c = 0; c < 5; c++) red[wave][c] = acc[c];
  __syncthreads();
  if (threadIdx.x < 5) {
    float s = red[0][threadIdx.x] + red[1][threadIdx.x] + red[2][threadIdx.x] + red[3][threadIdx.x];
    partial[blockIdx.x * 5 + threadIdx.x] = s;
  }
}

__global__ void fc_final_kernel(const float* __restrict__ partial, const float* __restrict__ fcb,
                                float* __restrict__ out) {
  __shared__ float red[4];
  __shared__ float logits[5];
  int tid = threadIdx.x;
  for (int c = 0; c < 5; c++) {
    float a = 0.f;
    for (int b = tid; b < FC_BLOCKS; b += 256) a += partial[b * 5 + c];
    #pragma unroll
    for (int msk = 1; msk <= 32; msk <<= 1) a += __shfl_xor(a, msk);
    if ((tid & 63) == 0) red[tid >> 6] = a;
    __syncthreads();
    if (tid == 0) logits[c] = red[0] + red[1] + red[2] + red[3] + fcb[c];
    __syncthreads();
  }
  if (tid == 0) {
    float mx = logits[0];
    for (int c = 1; c < 5; c++) mx = fmaxf(mx, logits[c]);
    float e[5], s = 0.f;
    for (int c = 0; c < 5; c++) { e[c] = expf(logits[c] - mx); s += e[c]; }
    for (int c = 0; c < 5; c++) out[c] = e[c] / s;
  }
}

// ---------------------------------------------------------------------------
extern "C" void kernel_launch(void* const* d_in, const int* in_sizes, int n_in,
                              void* d_out, int out_size, void* d_ws, size_t ws_size,
                              hipStream_t stream) {
  (void)in_sizes; (void)n_in; (void)out_size; (void)ws_size;
  const float* x   = (const float*)d_in[0];
  const int*   ei  = (const int*)d_in[1];
  const float* W1l = (const float*)d_in[2];
  const float* b1  = (const float*)d_in[3];
  const float* W1r = (const float*)d_in[4];
  const float* W2l = (const float*)d_in[5];
  const float* b2  = (const float*)d_in[6];
  const float* W2r = (const float*)d_in[7];
  const float* W3l = (const float*)d_in[8];
  const float* b3  = (const float*)d_in[9];
  const float* W3r = (const float*)d_in[10];
  const float* fcW = (const float*)d_in[11];
  const float* fcb = (const float*)d_in[12];
  const int* src = ei;
  const int* dst = ei + N_EDGES;

  char* ws = (char*)d_ws;
  size_t off = 0;
  auto alloc = [&](size_t bytes) { void* p = ws + off; off += (bytes + 255) & ~(size_t)255; return p; };
  int*   cnt     = (int*)alloc((size_t)N_NODES * 4);            // also reused as fill
  int*   row_ptr = (int*)alloc((size_t)(N_NODES + 1) * 4);
  int*   bsum    = (int*)alloc(512);
  float* inv_deg = (float*)alloc((size_t)N_NODES * 4);
  int*   col     = (int*)alloc((size_t)N_EDGES * 4);
  float* wt1     = (float*)alloc((size_t)256 * 256 * 4);
  float* wt2     = (float*)alloc((size_t)256 * 256 * 4);
  float* wt3     = (float*)alloc((size_t)128 * 128 * 4);
  float* partial = (float*)alloc((size_t)FC_BLOCKS * 5 * 4);
  float* R0      = (float*)alloc((size_t)N_NODES * 128 * 4);    // mean1 -> y2l -> y3l
  float* R1      = (float*)alloc((size_t)N_NODES * 256 * 4);    // h1 -> h2 -> h3
  float* R3      = (float*)alloc((size_t)N_NODES * 128 * 4);    // y2r -> y3r
  float* out5    = (float*)d_out;

  const int NCH = (N_NODES + 511) / 512;  // 98

  // ---- CSR build ----
  hipMemsetAsync(cnt, 0, (size_t)N_NODES * 4, stream);
  hist_kernel<<<(N_EDGES + 255) / 256, 256, 0, stream>>>(dst, cnt);
  chunk_sum_kernel<<<NCH, 512, 0, stream>>>(cnt, bsum);
  scan_bsum_kernel<<<1, 64, 0, stream>>>(bsum, NCH);
  scan_final_kernel<<<NCH, 512, 0, stream>>>(cnt, bsum, row_ptr, inv_deg);
  hipMemsetAsync(cnt, 0, (size_t)N_NODES * 4, stream);
  fill_csr_kernel<<<(N_EDGES + 255) / 256, 256, 0, stream>>>(src, dst, row_ptr, cnt, col);

  // ---- pack weights (transposed + concatenated) ----
  pack_kcat_kernel<<<(256 * 256) / 256, 256, 0, stream>>>(W1l, W1r, wt1, 128, 128, 256);
  pack_jcat_kernel<<<(256 * 256) / 256, 256, 0, stream>>>(W2l, W2r, wt2, 256, 128);
  pack_jcat_kernel<<<(128 * 128) / 256, 256, 0, stream>>>(W3l, W3r, wt3, 128, 64);

  const int GB = (N_NODES + 31) / 32;  // 1563 gemm blocks

  // ---- Layer 1: aggregate-first (128 -> 256) ----
  agg_mean_kernel<128><<<N_NODES, 128, 0, stream>>>(x, row_ptr, col, inv_deg, R0);
  // h1 = relu(l2norm([mean1|x] @ [W1l|W1r]^T + b1))  -> R1 [N,256]
  gemm_kernel<256, 256, true, 128, true, false><<<GB, 256, 0, stream>>>(R0, x, wt1, b1, R1, nullptr);

  // ---- Layer 2: transform-first (256 -> 128) ----
  // y2 = h1 @ [W2l;W2r]^T -> planes y2l=R0, y2r=R3 (each [N,128])
  gemm_kernel<256, 256, false, 256, false, true><<<GB, 256, 0, stream>>>(R1, nullptr, wt2, nullptr, R0, R3);
  // h2 = relu(l2norm(agg(y2l)/deg + b2 + y2r)) -> R1 [N,128]
  agg_norm_relu_kernel<128><<<N_NODES, 128, 0, stream>>>(R0, R3, b2, row_ptr, col, inv_deg, R1);

  // ---- Layer 3: transform-first (128 -> 64) ----
  gemm_kernel<128, 128, false, 128, false, true><<<GB, 256, 0, stream>>>(R1, nullptr, wt3, nullptr, R0, R3);
  // h3 = relu(l2norm(agg(y3l)/deg + b3 + y3r)) -> R1 [N,64]
  agg_norm_relu_kernel<64><<<N_NODES, 64, 0, stream>>>(R0, R3, b3, row_ptr, col, inv_deg, R1);

  // ---- FC + softmax ----
  fc_partial_kernel<<<FC_BLOCKS, 256, 0, stream>>>(fcW, R1, partial);
  fc_final_kernel<<<1, 256, 0, stream>>>(partial, fcb, out5);
}

// Round 2
// 357.920 us; speedup vs baseline: 1.4289x; 1.4289x over previous
//
#include <hip/hip_runtime.h>
#include <hip/hip_bf16.h>
#include <math.h>

#define N_NODES 50000
#define N_EDGES 500000
#define FC_BLOCKS 1024

typedef __bf16 bf16x8 __attribute__((ext_vector_type(8)));
typedef float f32x4 __attribute__((ext_vector_type(4)));
typedef unsigned int u32x4 __attribute__((ext_vector_type(4)));

static __device__ __forceinline__ float bf2f_lo(unsigned int v) {
  return __uint_as_float(v << 16);
}
static __device__ __forceinline__ float bf2f_hi(unsigned int v) {
  return __uint_as_float(v & 0xffff0000u);
}
static __device__ __forceinline__ unsigned short f2bf(float f) {
  unsigned int u = __float_as_uint(f);
  return (unsigned short)((u + 0x7fffu + ((u >> 16) & 1u)) >> 16);
}
static __device__ __forceinline__ bf16x8 ld8(const unsigned short* p) {
  u32x4 u = *(const u32x4*)p;
  return __builtin_bit_cast(bf16x8, u);
}

// ---------------------------------------------------------------------------
// CSR build
// ---------------------------------------------------------------------------
__global__ void hist_kernel(const int* __restrict__ dst, int* __restrict__ cnt) {
  int e = blockIdx.x * blockDim.x + threadIdx.x;
  if (e < N_EDGES) atomicAdd(&cnt[dst[e]], 1);
}

__global__ void chunk_sum_kernel(const int* __restrict__ cnt, int* __restrict__ bsum) {
  __shared__ int s[512];
  int i = blockIdx.x * 512 + threadIdx.x;
  s[threadIdx.x] = (i < N_NODES) ? cnt[i] : 0;
  __syncthreads();
  for (int off = 256; off > 0; off >>= 1) {
    if (threadIdx.x < off) s[threadIdx.x] += s[threadIdx.x + off];
    __syncthreads();
  }
  if (threadIdx.x == 0) bsum[blockIdx.x] = s[0];
}

__global__ void scan_bsum_kernel(int* __restrict__ bsum, int n) {
  if (blockIdx.x == 0 && threadIdx.x == 0) {
    int acc = 0;
    for (int i = 0; i < n; i++) { int v = bsum[i]; bsum[i] = acc; acc += v; }
  }
}

__global__ void scan_final_kernel(const int* __restrict__ cnt, const int* __restrict__ bsum,
                                  int* __restrict__ row_ptr, float* __restrict__ inv_deg) {
  __shared__ int s[512];
  int i = blockIdx.x * 512 + threadIdx.x;
  int v = (i < N_NODES) ? cnt[i] : 0;
  s[threadIdx.x] = v;
  __syncthreads();
  for (int off = 1; off < 512; off <<= 1) {
    int t = (threadIdx.x >= off) ? s[threadIdx.x - off] : 0;
    __syncthreads();
    s[threadIdx.x] += t;
    __syncthreads();
  }
  if (i < N_NODES) {
    row_ptr[i + 1] = bsum[blockIdx.x] + s[threadIdx.x];
    if (i == 0) row_ptr[0] = 0;
    inv_deg[i] = 1.0f / fmaxf((float)v, 1.0f);
  }
}

__global__ void fill_csr_kernel(const int* __restrict__ src, const int* __restrict__ dst,
                                const int* __restrict__ row_ptr, int* __restrict__ fill,
                                int* __restrict__ col) {
  int e = blockIdx.x * blockDim.x + threadIdx.x;
  if (e < N_EDGES) {
    int d = dst[e];
    int pos = row_ptr[d] + atomicAdd(&fill[d], 1);
    col[pos] = src[e];
  }
}

// ---------------------------------------------------------------------------
// fp32 -> bf16 convert
// ---------------------------------------------------------------------------
__global__ void f2b_kernel(const float* __restrict__ in, unsigned short* __restrict__ out, int n4) {
  int i = blockIdx.x * 256 + threadIdx.x;
  if (i < n4) {
    float4 v = ((const float4*)in)[i];
    ushort4 o;
    o.x = f2bf(v.x); o.y = f2bf(v.y); o.z = f2bf(v.z); o.w = f2bf(v.w);
    ((ushort4*)out)[i] = o;
  }
}

// ---------------------------------------------------------------------------
// Weight packing: [FO][FI] bf16 row-major (so B-frag reads are k-contiguous)
// kcat: cols = [Wl | Wr] (k concat). jcat: rows = [Wl ; Wr] (j concat).
// ---------------------------------------------------------------------------
__global__ void pack_kcat_kernel(const float* __restrict__ Wl, const float* __restrict__ Wr,
                                 unsigned short* __restrict__ Wt, int FIh, int FO) {
  int idx = blockIdx.x * 256 + threadIdx.x;
  int FI = 2 * FIh;
  if (idx < FI * FO) {
    int j = idx / FI, k = idx % FI;
    float v = (k < FIh) ? Wl[j * FIh + k] : Wr[j * FIh + (k - FIh)];
    Wt[idx] = f2bf(v);
  }
}

__global__ void pack_jcat_kernel(const float* __restrict__ Wl, const float* __restrict__ Wr,
                                 unsigned short* __restrict__ Wt, int FI, int FOh) {
  int idx = blockIdx.x * 256 + threadIdx.x;
  if (idx < 2 * FOh * FI) {
    int j = idx / FI, k = idx % FI;
    float v = (j < FOh) ? Wl[j * FI + k] : Wr[(j - FOh) * FI + k];
    Wt[idx] = f2bf(v);
  }
}

// ---------------------------------------------------------------------------
// Aggregation (bf16 gather, fp32 accum). One wave per node.
// ---------------------------------------------------------------------------
__global__ void agg_mean_bf16(const unsigned short* __restrict__ xb, const int* __restrict__ rp,
                              const int* __restrict__ cl, const float* __restrict__ idg,
                              unsigned short* __restrict__ out) {
  int node = blockIdx.x * 4 + (threadIdx.x >> 6);
  int lane = threadIdx.x & 63;
  int beg = rp[node], end = rp[node + 1];
  float a0 = 0.f, a1 = 0.f;
  for (int e = beg; e < end; e++) {
    int c = cl[e];
    unsigned int v = *(const unsigned int*)(xb + (size_t)c * 128 + lane * 2);
    a0 += bf2f_lo(v); a1 += bf2f_hi(v);
  }
  float g = idg[node];
  unsigned int o = (unsigned int)f2bf(a0 * g) | ((unsigned int)f2bf(a1 * g) << 16);
  *(unsigned int*)(out + (size_t)node * 128 + lane * 2) = o;
}

// out = relu(l2norm( mean_gather(yl) + bias + yr_row )); F in {128,64}
template<int F, bool OUTF32>
__global__ void agg_nr_bf16(const unsigned short* __restrict__ yl, const unsigned short* __restrict__ yr,
                            const float* __restrict__ bias, const int* __restrict__ rp,
                            const int* __restrict__ cl, const float* __restrict__ idg,
                            unsigned short* __restrict__ outb, float* __restrict__ outf) {
  constexpr int V = F / 64;  // 2 or 1
  int node = blockIdx.x * 4 + (threadIdx.x >> 6);
  int lane = threadIdx.x & 63;
  int beg = rp[node], end = rp[node + 1];
  float a0 = 0.f, a1 = 0.f;
  for (int e = beg; e < end; e++) {
    int c = cl[e];
    if (V == 2) {
      unsigned int v = *(const unsigned int*)(yl + (size_t)c * F + lane * 2);
      a0 += bf2f_lo(v); a1 += bf2f_hi(v);
    } else {
      a0 += bf2f_lo((unsigned int)yl[(size_t)c * F + lane]);
    }
  }
  float g = idg[node];
  float v0, v1 = 0.f;
  if (V == 2) {
    unsigned int r = *(const unsigned int*)(yr + (size_t)node * F + lane * 2);
    v0 = a0 * g + bias[lane * 2 + 0] + bf2f_lo(r);
    v1 = a1 * g + bias[lane * 2 + 1] + bf2f_hi(r);
  } else {
    v0 = a0 * g + bias[lane] + bf2f_lo((unsigned int)yr[(size_t)node * F + lane]);
  }
  float p = v0 * v0 + v1 * v1;
  #pragma unroll
  for (int msk = 1; msk <= 32; msk <<= 1) p += __shfl_xor(p, msk);
  float sc = 1.0f / fmaxf(sqrtf(p), 1e-12f);
  v0 = fmaxf(v0 * sc, 0.f);
  v1 = fmaxf(v1 * sc, 0.f);
  if (OUTF32) {
    if (V == 2) {
      outf[(size_t)node * F + lane * 2 + 0] = v0;
      outf[(size_t)node * F + lane * 2 + 1] = v1;
    } else {
      outf[(size_t)node * F + lane] = v0;
    }
  } else {
    if (V == 2) {
      unsigned int o = (unsigned int)f2bf(v0) | ((unsigned int)f2bf(v1) << 16);
      *(unsigned int*)(outb + (size_t)node * F + lane * 2) = o;
    } else {
      outb[(size_t)node * F + lane] = f2bf(v0);
    }
  }
}

// ---------------------------------------------------------------------------
// MFMA GEMM: out[N,FO] = A[N,FI](bf16) @ W[FO][FI](bf16)^T
// Block: 256 thr = 4 waves; tile 64 rows x FO cols (wave owns FO/4 cols).
// Operands read directly from global (W is L2-resident; A-frags are 64B/row).
// POST: +bias, L2-normalize over FO, relu. OSPLIT: col halves to outA/outB.
// ---------------------------------------------------------------------------
template<int FI, int FO, bool ASPLIT, bool POST, bool OSPLIT>
__launch_bounds__(256)
__global__ void mfma_gemm(const unsigned short* __restrict__ A1, const unsigned short* __restrict__ A2,
                          const unsigned short* __restrict__ W, const float* __restrict__ bias,
                          unsigned short* __restrict__ outA, unsigned short* __restrict__ outB) {
  constexpr int CF = FO / 64;            // col frags per wave
  constexpr int ASTR = ASPLIT ? FI / 2 : FI;
  __shared__ float sums[64][5];
  const int tid = threadIdx.x;
  const int wave = tid >> 6, lane = tid & 63;
  const int l15 = lane & 15, kg = lane >> 4;
  const int row0 = blockIdx.x * 64;
  const int colbase = wave * (FO / 4);

  f32x4 acc[4][CF];
  #pragma unroll
  for (int rf = 0; rf < 4; rf++)
    #pragma unroll
    for (int cf = 0; cf < CF; cf++) acc[rf][cf] = (f32x4){0.f, 0.f, 0.f, 0.f};

  int rowIdx[4];
  #pragma unroll
  for (int rf = 0; rf < 4; rf++) {
    int r = row0 + rf * 16 + l15;
    rowIdx[rf] = (r < N_NODES) ? r : (N_NODES - 1);
  }

  for (int k0 = 0; k0 < FI; k0 += 32) {
    const int kf = k0 + kg * 8;
    const unsigned short* Ap = A1; int kl = kf;
    if (ASPLIT && k0 >= FI / 2) { Ap = A2; kl = kf - FI / 2; }
    bf16x8 a[4], b[CF];
    #pragma unroll
    for (int rf = 0; rf < 4; rf++) a[rf] = ld8(Ap + (size_t)rowIdx[rf] * ASTR + kl);
    #pragma unroll
    for (int cf = 0; cf < CF; cf++) b[cf] = ld8(W + (size_t)(colbase + cf * 16 + l15) * FI + kf);
    #pragma unroll
    for (int rf = 0; rf < 4; rf++)
      #pragma unroll
      for (int cf = 0; cf < CF; cf++)
        acc[rf][cf] = __builtin_amdgcn_mfma_f32_16x16x32_bf16(a[rf], b[cf], acc[rf][cf], 0, 0, 0);
  }

  if (POST) {
    float bj[CF];
    #pragma unroll
    for (int cf = 0; cf < CF; cf++) bj[cf] = bias[colbase + cf * 16 + l15];
    float p[4][4];
    #pragma unroll
    for (int rf = 0; rf < 4; rf++)
      #pragma unroll
      for (int r = 0; r < 4; r++) p[rf][r] = 0.f;
    #pragma unroll
    for (int rf = 0; rf < 4; rf++)
      #pragma unroll
      for (int cf = 0; cf < CF; cf++)
        #pragma unroll
        for (int r = 0; r < 4; r++) {
          float v = acc[rf][cf][r] + bj[cf];
          acc[rf][cf][r] = v;
          p[rf][r] += v * v;
        }
    #pragma unroll
    for (int msk = 1; msk <= 8; msk <<= 1)
      #pragma unroll
      for (int rf = 0; rf < 4; rf++)
        #pragma unroll
        for (int r = 0; r < 4; r++) p[rf][r] += __shfl_xor(p[rf][r], msk);
    if (l15 == 0) {
      #pragma unroll
      for (int rf = 0; rf < 4; rf++)
        #pragma unroll
        for (int r = 0; r < 4; r++) sums[rf * 16 + kg * 4 + r][wave] = p[rf][r];
    }
    __syncthreads();
    #pragma unroll
    for (int rf = 0; rf < 4; rf++)
      #pragma unroll
      for (int r = 0; r < 4; r++) {
        int rl = rf * 16 + kg * 4 + r;
        float tot = sums[rl][0] + sums[rl][1] + sums[rl][2] + sums[rl][3];
        float sc = 1.0f / fmaxf(sqrtf(tot), 1e-12f);
        #pragma unroll
        for (int cf = 0; cf < CF; cf++) acc[rf][cf][r] = fmaxf(acc[rf][cf][r] * sc, 0.f);
      }
  }

  unsigned short* ob = outA;
  int cb = colbase;
  constexpr int OSTR = OSPLIT ? FO / 2 : FO;
  if (OSPLIT && colbase >= FO / 2) { ob = outB; cb = colbase - FO / 2; }
  #pragma unroll
  for (int rf = 0; rf < 4; rf++)
    #pragma unroll
    for (int r = 0; r < 4; r++) {
      int row = row0 + rf * 16 + kg * 4 + r;
      if (row < N_NODES) {
        #pragma unroll
        for (int cf = 0; cf < CF; cf++)
          ob[(size_t)row * OSTR + cb + cf * 16 + l15] = f2bf(acc[rf][cf][r]);
      }
    }
}

// ---------------------------------------------------------------------------
// FC: logits = fcW @ h3.flat + fcb; softmax
// ---------------------------------------------------------------------------
__global__ void fc_partial_kernel(const float* __restrict__ fcW, const float* __restrict__ h3,
                                  float* __restrict__ partial) {
  const size_t L = (size_t)N_NODES * 64;
  float acc[5] = {0.f, 0.f, 0.f, 0.f, 0.f};
  for (size_t i = (size_t)blockIdx.x * 256 + threadIdx.x; i < L; i += (size_t)gridDim.x * 256) {
    float h = h3[i];
    #pragma unroll
    for (int c = 0; c < 5; c++) acc[c] += h * fcW[(size_t)c * L + i];
  }
  __shared__ float red[4][5];
  #pragma unroll
  for (int msk = 1; msk <= 32; msk <<= 1)
    #pragma unroll
    for (int c = 0; c < 5; c++) acc[c] += __shfl_xor(acc[c], msk);
  int lane = threadIdx.x & 63, wave = threadIdx.x >> 6;
  if (lane == 0)
    #pragma unroll
    for (int c = 0; c < 5; c++) red[wave][c] = acc[c];
  __syncthreads();
  if (threadIdx.x < 5) {
    float s = red[0][threadIdx.x] + red[1][threadIdx.x] + red[2][threadIdx.x] + red[3][threadIdx.x];
    partial[blockIdx.x * 5 + threadIdx.x] = s;
  }
}

__global__ void fc_final_kernel(const float* __restrict__ partial, const float* __restrict__ fcb,
                                float* __restrict__ out) {
  __shared__ float red[4];
  __shared__ float logits[5];
  int tid = threadIdx.x;
  for (int c = 0; c < 5; c++) {
    float a = 0.f;
    for (int b = tid; b < FC_BLOCKS; b += 256) a += partial[b * 5 + c];
    #pragma unroll
    for (int msk = 1; msk <= 32; msk <<= 1) a += __shfl_xor(a, msk);
    if ((tid & 63) == 0) red[tid >> 6] = a;
    __syncthreads();
    if (tid == 0) logits[c] = red[0] + red[1] + red[2] + red[3] + fcb[c];
    __syncthreads();
  }
  if (tid == 0) {
    float mx = logits[0];
    for (int c = 1; c < 5; c++) mx = fmaxf(mx, logits[c]);
    float e[5], s = 0.f;
    for (int c = 0; c < 5; c++) { e[c] = expf(logits[c] - mx); s += e[c]; }
    for (int c = 0; c < 5; c++) out[c] = e[c] / s;
  }
}

// ---------------------------------------------------------------------------
extern "C" void kernel_launch(void* const* d_in, const int* in_sizes, int n_in,
                              void* d_out, int out_size, void* d_ws, size_t ws_size,
                              hipStream_t stream) {
  (void)in_sizes; (void)n_in; (void)out_size; (void)ws_size;
  const float* x   = (const float*)d_in[0];
  const int*   ei  = (const int*)d_in[1];
  const float* W1l = (const float*)d_in[2];
  const float* b1  = (const float*)d_in[3];
  const float* W1r = (const float*)d_in[4];
  const float* W2l = (const float*)d_in[5];
  const float* b2  = (const float*)d_in[6];
  const float* W2r = (const float*)d_in[7];
  const float* W3l = (const float*)d_in[8];
  const float* b3  = (const float*)d_in[9];
  const float* W3r = (const float*)d_in[10];
  const float* fcW = (const float*)d_in[11];
  const float* fcb = (const float*)d_in[12];
  const int* src = ei;
  const int* dst = ei + N_EDGES;

  char* ws = (char*)d_ws;
  size_t off = 0;
  auto alloc = [&](size_t bytes) { void* p = ws + off; off += (bytes + 255) & ~(size_t)255; return p; };
  int*   cnt     = (int*)alloc((size_t)N_NODES * 4);
  int*   row_ptr = (int*)alloc((size_t)(N_NODES + 1) * 4);
  int*   bsum    = (int*)alloc(512);
  float* inv_deg = (float*)alloc((size_t)N_NODES * 4);
  int*   col     = (int*)alloc((size_t)N_EDGES * 4);
  unsigned short* w1b = (unsigned short*)alloc((size_t)256 * 256 * 2);
  unsigned short* w2b = (unsigned short*)alloc((size_t)256 * 256 * 2);
  unsigned short* w3b = (unsigned short*)alloc((size_t)128 * 128 * 2);
  float* partial = (float*)alloc((size_t)FC_BLOCKS * 5 * 4);
  unsigned short* B0 = (unsigned short*)alloc((size_t)N_NODES * 128 * 2);  // xb -> y2r
  unsigned short* B1 = (unsigned short*)alloc((size_t)N_NODES * 128 * 2);  // mean1 -> y2l
  unsigned short* B2 = (unsigned short*)alloc((size_t)N_NODES * 256 * 2);  // h1 -> {y3l, y3r}
  unsigned short* B3 = (unsigned short*)alloc((size_t)N_NODES * 128 * 2);  // h2
  float* B4 = (float*)alloc((size_t)N_NODES * 64 * 4);                      // h3 (fp32 for FC)
  float* out5 = (float*)d_out;

  unsigned short* xb    = B0;
  unsigned short* mean1 = B1;
  unsigned short* h1    = B2;
  unsigned short* y2l   = B1;
  unsigned short* y2r   = B0;
  unsigned short* h2    = B3;
  unsigned short* y3l   = B2;
  unsigned short* y3r   = B2 + (size_t)N_NODES * 64;
  float*          h3f   = B4;

  const int NCH = (N_NODES + 511) / 512;  // 98

  // ---- CSR build ----
  hipMemsetAsync(cnt, 0, (size_t)N_NODES * 4, stream);
  hist_kernel<<<(N_EDGES + 255) / 256, 256, 0, stream>>>(dst, cnt);
  chunk_sum_kernel<<<NCH, 512, 0, stream>>>(cnt, bsum);
  scan_bsum_kernel<<<1, 64, 0, stream>>>(bsum, NCH);
  scan_final_kernel<<<NCH, 512, 0, stream>>>(cnt, bsum, row_ptr, inv_deg);
  hipMemsetAsync(cnt, 0, (size_t)N_NODES * 4, stream);
  fill_csr_kernel<<<(N_EDGES + 255) / 256, 256, 0, stream>>>(src, dst, row_ptr, cnt, col);

  // ---- x -> bf16, pack weights ----
  f2b_kernel<<<(N_NODES * 128 / 4 + 255) / 256, 256, 0, stream>>>(x, xb, N_NODES * 128 / 4);
  pack_kcat_kernel<<<(256 * 256 + 255) / 256, 256, 0, stream>>>(W1l, W1r, w1b, 128, 256);
  pack_jcat_kernel<<<(256 * 256 + 255) / 256, 256, 0, stream>>>(W2l, W2r, w2b, 256, 128);
  pack_jcat_kernel<<<(128 * 128 + 255) / 256, 256, 0, stream>>>(W3l, W3r, w3b, 128, 64);

  const int AGB = N_NODES / 4;            // 12500 (4 waves/block, 1 node/wave)
  const int GB  = (N_NODES + 63) / 64;    // 782

  // ---- Layer 1: aggregate-first (128 -> 256) ----
  agg_mean_bf16<<<AGB, 256, 0, stream>>>(xb, row_ptr, col, inv_deg, mean1);
  mfma_gemm<256, 256, true, true, false><<<GB, 256, 0, stream>>>(mean1, xb, w1b, b1, h1, nullptr);

  // ---- Layer 2: transform-first (256 -> 128) ----
  mfma_gemm<256, 256, false, false, true><<<GB, 256, 0, stream>>>(h1, nullptr, w2b, nullptr, y2l, y2r);
  agg_nr_bf16<128, false><<<AGB, 256, 0, stream>>>(y2l, y2r, b2, row_ptr, col, inv_deg, h2, nullptr);

  // ---- Layer 3: transform-first (128 -> 64) ----
  mfma_gemm<128, 128, false, false, true><<<GB, 256, 0, stream>>>(h2, nullptr, w3b, nullptr, y3l, y3r);
  agg_nr_bf16<64, true><<<AGB, 256, 0, stream>>>(y3l, y3r, b3, row_ptr, col, inv_deg, nullptr, h3f);

  // ---- FC + softmax ----
  fc_partial_kernel<<<FC_BLOCKS, 256, 0, stream>>>(fcW, h3f, partial);
  fc_final_kernel<<<1, 256, 0, stream>>>(partial, fcb, out5);
}

// Round 3
// 275.611 us; speedup vs baseline: 1.8556x; 1.2986x over previous
//
#include <hip/hip_runtime.h>
#include <hip/hip_bf16.h>
#include <math.h>

#define N_NODES 50000
#define N_EDGES 500000
#define FC_BLOCKS 1024

typedef __bf16 bf16x8 __attribute__((ext_vector_type(8)));
typedef float f32x4 __attribute__((ext_vector_type(4)));
typedef unsigned int u32x4 __attribute__((ext_vector_type(4)));

static __device__ __forceinline__ float bf2f_lo(unsigned int v) {
  return __uint_as_float(v << 16);
}
static __device__ __forceinline__ float bf2f_hi(unsigned int v) {
  return __uint_as_float(v & 0xffff0000u);
}
static __device__ __forceinline__ unsigned short f2bf(float f) {
  unsigned int u = __float_as_uint(f);
  return (unsigned short)((u + 0x7fffu + ((u >> 16) & 1u)) >> 16);
}
static __device__ __forceinline__ bf16x8 ld8(const unsigned short* p) {
  u32x4 u = *(const u32x4*)p;
  return __builtin_bit_cast(bf16x8, u);
}

// ---------------------------------------------------------------------------
// CSR build
// ---------------------------------------------------------------------------
__global__ void hist_kernel(const int* __restrict__ dst, int* __restrict__ cnt) {
  int e = blockIdx.x * blockDim.x + threadIdx.x;
  if (e < N_EDGES) atomicAdd(&cnt[dst[e]], 1);
}

__global__ void chunk_sum_kernel(const int* __restrict__ cnt, int* __restrict__ bsum) {
  __shared__ int s[512];
  int i = blockIdx.x * 512 + threadIdx.x;
  s[threadIdx.x] = (i < N_NODES) ? cnt[i] : 0;
  __syncthreads();
  for (int off = 256; off > 0; off >>= 1) {
    if (threadIdx.x < off) s[threadIdx.x] += s[threadIdx.x + off];
    __syncthreads();
  }
  if (threadIdx.x == 0) bsum[blockIdx.x] = s[0];
}

__global__ void scan_bsum_kernel(int* __restrict__ bsum, int n) {
  if (blockIdx.x == 0 && threadIdx.x == 0) {
    int acc = 0;
    for (int i = 0; i < n; i++) { int v = bsum[i]; bsum[i] = acc; acc += v; }
  }
}

__global__ void scan_final_kernel(const int* __restrict__ cnt, const int* __restrict__ bsum,
                                  int* __restrict__ row_ptr, float* __restrict__ inv_deg) {
  __shared__ int s[512];
  int i = blockIdx.x * 512 + threadIdx.x;
  int v = (i < N_NODES) ? cnt[i] : 0;
  s[threadIdx.x] = v;
  __syncthreads();
  for (int off = 1; off < 512; off <<= 1) {
    int t = (threadIdx.x >= off) ? s[threadIdx.x - off] : 0;
    __syncthreads();
    s[threadIdx.x] += t;
    __syncthreads();
  }
  if (i < N_NODES) {
    row_ptr[i + 1] = bsum[blockIdx.x] + s[threadIdx.x];
    if (i == 0) row_ptr[0] = 0;
    inv_deg[i] = 1.0f / fmaxf((float)v, 1.0f);
  }
}

__global__ void fill_csr_kernel(const int* __restrict__ src, const int* __restrict__ dst,
                                const int* __restrict__ row_ptr, int* __restrict__ fill,
                                int* __restrict__ col) {
  int e = blockIdx.x * blockDim.x + threadIdx.x;
  if (e < N_EDGES) {
    int d = dst[e];
    int pos = row_ptr[d] + atomicAdd(&fill[d], 1);
    col[pos] = src[e];
  }
}

// ---------------------------------------------------------------------------
// fp32 -> bf16 convert
// ---------------------------------------------------------------------------
__global__ void f2b_kernel(const float* __restrict__ in, unsigned short* __restrict__ out, int n4) {
  int i = blockIdx.x * 256 + threadIdx.x;
  if (i < n4) {
    float4 v = ((const float4*)in)[i];
    ushort4 o;
    o.x = f2bf(v.x); o.y = f2bf(v.y); o.z = f2bf(v.z); o.w = f2bf(v.w);
    ((ushort4*)out)[i] = o;
  }
}

// ---------------------------------------------------------------------------
// Weight packing: [FO][FI] bf16 row-major
// ---------------------------------------------------------------------------
__global__ void pack_kcat_kernel(const float* __restrict__ Wl, const float* __restrict__ Wr,
                                 unsigned short* __restrict__ Wt, int FIh, int FO) {
  int idx = blockIdx.x * 256 + threadIdx.x;
  int FI = 2 * FIh;
  if (idx < FI * FO) {
    int j = idx / FI, k = idx % FI;
    float v = (k < FIh) ? Wl[j * FIh + k] : Wr[j * FIh + (k - FIh)];
    Wt[idx] = f2bf(v);
  }
}

__global__ void pack_jcat_kernel(const float* __restrict__ Wl, const float* __restrict__ Wr,
                                 unsigned short* __restrict__ Wt, int FI, int FOh) {
  int idx = blockIdx.x * 256 + threadIdx.x;
  if (idx < 2 * FOh * FI) {
    int j = idx / FI, k = idx % FI;
    float v = (j < FOh) ? Wl[j * FI + k] : Wr[(j - FOh) * FI + k];
    Wt[idx] = f2bf(v);
  }
}

// ---------------------------------------------------------------------------
// Aggregation: 1 wave per node, 16-lane groups gather DIFFERENT edges in
// parallel (2 edges in flight per group) -> 8/16 independent 16B loads per
// wave per iteration instead of 1x4B. fp32 accumulate, cross-group shfl merge.
// ---------------------------------------------------------------------------
#define ACC8(v)                                          \
  do {                                                   \
    a[0] += bf2f_lo((v)[0]); a[1] += bf2f_hi((v)[0]);    \
    a[2] += bf2f_lo((v)[1]); a[3] += bf2f_hi((v)[1]);    \
    a[4] += bf2f_lo((v)[2]); a[5] += bf2f_hi((v)[2]);    \
    a[6] += bf2f_lo((v)[3]); a[7] += bf2f_hi((v)[3]);    \
  } while (0)

__global__ void agg_mean_bf16(const unsigned short* __restrict__ xb, const int* __restrict__ rp,
                              const int* __restrict__ cl, const float* __restrict__ idg,
                              unsigned short* __restrict__ out) {
  int node = blockIdx.x * 4 + (threadIdx.x >> 6);
  int lane = threadIdx.x & 63;
  int g = lane >> 4, l = lane & 15;
  int beg = rp[node], end = rp[node + 1];
  float a[8] = {0.f, 0.f, 0.f, 0.f, 0.f, 0.f, 0.f, 0.f};
  for (int e0 = beg; e0 < end; e0 += 8) {
    int e1 = e0 + g, e2 = e0 + 4 + g;
    if (e1 < end) {
      u32x4 v = *(const u32x4*)(xb + (size_t)cl[e1] * 128 + l * 8);
      ACC8(v);
    }
    if (e2 < end) {
      u32x4 v = *(const u32x4*)(xb + (size_t)cl[e2] * 128 + l * 8);
      ACC8(v);
    }
  }
  #pragma unroll
  for (int i = 0; i < 8; i++) {
    a[i] += __shfl_xor(a[i], 16);
    a[i] += __shfl_xor(a[i], 32);
  }
  if (g == 0) {
    float s = idg[node];
    u32x4 o;
    #pragma unroll
    for (int i = 0; i < 4; i++)
      o[i] = (unsigned int)f2bf(a[2 * i] * s) | ((unsigned int)f2bf(a[2 * i + 1] * s) << 16);
    *(u32x4*)(out + (size_t)node * 128 + l * 8) = o;
  }
}

// h = relu(l2norm(mean_gather(yl) + bias + yr_row)), F=128, bf16 out
__global__ void agg_nr128(const unsigned short* __restrict__ yl, const unsigned short* __restrict__ yr,
                          const float* __restrict__ bias, const int* __restrict__ rp,
                          const int* __restrict__ cl, const float* __restrict__ idg,
                          unsigned short* __restrict__ outb) {
  int node = blockIdx.x * 4 + (threadIdx.x >> 6);
  int lane = threadIdx.x & 63;
  int g = lane >> 4, l = lane & 15;
  int beg = rp[node], end = rp[node + 1];
  float a[8] = {0.f, 0.f, 0.f, 0.f, 0.f, 0.f, 0.f, 0.f};
  for (int e0 = beg; e0 < end; e0 += 8) {
    int e1 = e0 + g, e2 = e0 + 4 + g;
    if (e1 < end) {
      u32x4 v = *(const u32x4*)(yl + (size_t)cl[e1] * 128 + l * 8);
      ACC8(v);
    }
    if (e2 < end) {
      u32x4 v = *(const u32x4*)(yl + (size_t)cl[e2] * 128 + l * 8);
      ACC8(v);
    }
  }
  #pragma unroll
  for (int i = 0; i < 8; i++) {
    a[i] += __shfl_xor(a[i], 16);
    a[i] += __shfl_xor(a[i], 32);
  }
  float s = idg[node];
  u32x4 r = *(const u32x4*)(yr + (size_t)node * 128 + l * 8);
  float v[8];
  v[0] = a[0] * s + bias[l * 8 + 0] + bf2f_lo(r[0]);
  v[1] = a[1] * s + bias[l * 8 + 1] + bf2f_hi(r[0]);
  v[2] = a[2] * s + bias[l * 8 + 2] + bf2f_lo(r[1]);
  v[3] = a[3] * s + bias[l * 8 + 3] + bf2f_hi(r[1]);
  v[4] = a[4] * s + bias[l * 8 + 4] + bf2f_lo(r[2]);
  v[5] = a[5] * s + bias[l * 8 + 5] + bf2f_hi(r[2]);
  v[6] = a[6] * s + bias[l * 8 + 6] + bf2f_lo(r[3]);
  v[7] = a[7] * s + bias[l * 8 + 7] + bf2f_hi(r[3]);
  float p = 0.f;
  #pragma unroll
  for (int i = 0; i < 8; i++) p += v[i] * v[i];
  #pragma unroll
  for (int msk = 1; msk <= 8; msk <<= 1) p += __shfl_xor(p, msk);
  float sc = 1.0f / fmaxf(sqrtf(p), 1e-12f);
  if (g == 0) {
    u32x4 o;
    #pragma unroll
    for (int i = 0; i < 4; i++) {
      float w0 = fmaxf(v[2 * i] * sc, 0.f);
      float w1 = fmaxf(v[2 * i + 1] * sc, 0.f);
      o[i] = (unsigned int)f2bf(w0) | ((unsigned int)f2bf(w1) << 16);
    }
    *(u32x4*)(outb + (size_t)node * 128 + l * 8) = o;
  }
}

// h = relu(l2norm(mean_gather(yl) + bias + yr_row)), F=64, fp32 out
__global__ void agg_nr64(const unsigned short* __restrict__ yl, const unsigned short* __restrict__ yr,
                         const float* __restrict__ bias, const int* __restrict__ rp,
                         const int* __restrict__ cl, const float* __restrict__ idg,
                         float* __restrict__ outf) {
  int node = blockIdx.x * 4 + (threadIdx.x >> 6);
  int lane = threadIdx.x & 63;
  int g = lane >> 3, l = lane & 7;
  int beg = rp[node], end = rp[node + 1];
  float a[8] = {0.f, 0.f, 0.f, 0.f, 0.f, 0.f, 0.f, 0.f};
  for (int e0 = beg; e0 < end; e0 += 16) {
    int e1 = e0 + g, e2 = e0 + 8 + g;
    if (e1 < end) {
      u32x4 v = *(const u32x4*)(yl + (size_t)cl[e1] * 64 + l * 8);
      ACC8(v);
    }
    if (e2 < end) {
      u32x4 v = *(const u32x4*)(yl + (size_t)cl[e2] * 64 + l * 8);
      ACC8(v);
    }
  }
  #pragma unroll
  for (int i = 0; i < 8; i++) {
    a[i] += __shfl_xor(a[i], 8);
    a[i] += __shfl_xor(a[i], 16);
    a[i] += __shfl_xor(a[i], 32);
  }
  float s = idg[node];
  u32x4 r = *(const u32x4*)(yr + (size_t)node * 64 + l * 8);
  float v[8];
  v[0] = a[0] * s + bias[l * 8 + 0] + bf2f_lo(r[0]);
  v[1] = a[1] * s + bias[l * 8 + 1] + bf2f_hi(r[0]);
  v[2] = a[2] * s + bias[l * 8 + 2] + bf2f_lo(r[1]);
  v[3] = a[3] * s + bias[l * 8 + 3] + bf2f_hi(r[1]);
  v[4] = a[4] * s + bias[l * 8 + 4] + bf2f_lo(r[2]);
  v[5] = a[5] * s + bias[l * 8 + 5] + bf2f_hi(r[2]);
  v[6] = a[6] * s + bias[l * 8 + 6] + bf2f_lo(r[3]);
  v[7] = a[7] * s + bias[l * 8 + 7] + bf2f_hi(r[3]);
  float p = 0.f;
  #pragma unroll
  for (int i = 0; i < 8; i++) p += v[i] * v[i];
  #pragma unroll
  for (int msk = 1; msk <= 4; msk <<= 1) p += __shfl_xor(p, msk);
  float sc = 1.0f / fmaxf(sqrtf(p), 1e-12f);
  if (g == 0) {
    f32x4 o0, o1;
    #pragma unroll
    for (int i = 0; i < 4; i++) o0[i] = fmaxf(v[i] * sc, 0.f);
    #pragma unroll
    for (int i = 0; i < 4; i++) o1[i] = fmaxf(v[4 + i] * sc, 0.f);
    *(f32x4*)(outf + (size_t)node * 64 + l * 8) = o0;
    *(f32x4*)(outf + (size_t)node * 64 + l * 8 + 4) = o1;
  }
}

// ---------------------------------------------------------------------------
// MFMA GEMM: out[N,FO] = A[N,FI](bf16) @ W[FO][FI](bf16)^T
// ---------------------------------------------------------------------------
template<int FI, int FO, bool ASPLIT, bool POST, bool OSPLIT>
__launch_bounds__(256)
__global__ void mfma_gemm(const unsigned short* __restrict__ A1, const unsigned short* __restrict__ A2,
                          const unsigned short* __restrict__ W, const float* __restrict__ bias,
                          unsigned short* __restrict__ outA, unsigned short* __restrict__ outB) {
  constexpr int CF = FO / 64;            // col frags per wave
  constexpr int ASTR = ASPLIT ? FI / 2 : FI;
  __shared__ float sums[64][5];
  const int tid = threadIdx.x;
  const int wave = tid >> 6, lane = tid & 63;
  const int l15 = lane & 15, kg = lane >> 4;
  const int row0 = blockIdx.x * 64;
  const int colbase = wave * (FO / 4);

  f32x4 acc[4][CF];
  #pragma unroll
  for (int rf = 0; rf < 4; rf++)
    #pragma unroll
    for (int cf = 0; cf < CF; cf++) acc[rf][cf] = (f32x4){0.f, 0.f, 0.f, 0.f};

  int rowIdx[4];
  #pragma unroll
  for (int rf = 0; rf < 4; rf++) {
    int r = row0 + rf * 16 + l15;
    rowIdx[rf] = (r < N_NODES) ? r : (N_NODES - 1);
  }

  for (int k0 = 0; k0 < FI; k0 += 32) {
    const int kf = k0 + kg * 8;
    const unsigned short* Ap = A1; int kl = kf;
    if (ASPLIT && k0 >= FI / 2) { Ap = A2; kl = kf - FI / 2; }
    bf16x8 a[4], b[CF];
    #pragma unroll
    for (int rf = 0; rf < 4; rf++) a[rf] = ld8(Ap + (size_t)rowIdx[rf] * ASTR + kl);
    #pragma unroll
    for (int cf = 0; cf < CF; cf++) b[cf] = ld8(W + (size_t)(colbase + cf * 16 + l15) * FI + kf);
    #pragma unroll
    for (int rf = 0; rf < 4; rf++)
      #pragma unroll
      for (int cf = 0; cf < CF; cf++)
        acc[rf][cf] = __builtin_amdgcn_mfma_f32_16x16x32_bf16(a[rf], b[cf], acc[rf][cf], 0, 0, 0);
  }

  if (POST) {
    float bj[CF];
    #pragma unroll
    for (int cf = 0; cf < CF; cf++) bj[cf] = bias[colbase + cf * 16 + l15];
    float p[4][4];
    #pragma unroll
    for (int rf = 0; rf < 4; rf++)
      #pragma unroll
      for (int r = 0; r < 4; r++) p[rf][r] = 0.f;
    #pragma unroll
    for (int rf = 0; rf < 4; rf++)
      #pragma unroll
      for (int cf = 0; cf < CF; cf++)
        #pragma unroll
        for (int r = 0; r < 4; r++) {
          float v = acc[rf][cf][r] + bj[cf];
          acc[rf][cf][r] = v;
          p[rf][r] += v * v;
        }
    #pragma unroll
    for (int msk = 1; msk <= 8; msk <<= 1)
      #pragma unroll
      for (int rf = 0; rf < 4; rf++)
        #pragma unroll
        for (int r = 0; r < 4; r++) p[rf][r] += __shfl_xor(p[rf][r], msk);
    if (l15 == 0) {
      #pragma unroll
      for (int rf = 0; rf < 4; rf++)
        #pragma unroll
        for (int r = 0; r < 4; r++) sums[rf * 16 + kg * 4 + r][wave] = p[rf][r];
    }
    __syncthreads();
    #pragma unroll
    for (int rf = 0; rf < 4; rf++)
      #pragma unroll
      for (int r = 0; r < 4; r++) {
        int rl = rf * 16 + kg * 4 + r;
        float tot = sums[rl][0] + sums[rl][1] + sums[rl][2] + sums[rl][3];
        float sc = 1.0f / fmaxf(sqrtf(tot), 1e-12f);
        #pragma unroll
        for (int cf = 0; cf < CF; cf++) acc[rf][cf][r] = fmaxf(acc[rf][cf][r] * sc, 0.f);
      }
  }

  unsigned short* ob = outA;
  int cb = colbase;
  constexpr int OSTR = OSPLIT ? FO / 2 : FO;
  if (OSPLIT && colbase >= FO / 2) { ob = outB; cb = colbase - FO / 2; }
  #pragma unroll
  for (int rf = 0; rf < 4; rf++)
    #pragma unroll
    for (int r = 0; r < 4; r++) {
      int row = row0 + rf * 16 + kg * 4 + r;
      if (row < N_NODES) {
        #pragma unroll
        for (int cf = 0; cf < CF; cf++)
          ob[(size_t)row * OSTR + cb + cf * 16 + l15] = f2bf(acc[rf][cf][r]);
      }
    }
}

// ---------------------------------------------------------------------------
// FC: logits = fcW @ h3.flat + fcb; softmax
// ---------------------------------------------------------------------------
__global__ void fc_partial_kernel(const float* __restrict__ fcW, const float* __restrict__ h3,
                                  float* __restrict__ partial) {
  const size_t L = (size_t)N_NODES * 64;
  float acc[5] = {0.f, 0.f, 0.f, 0.f, 0.f};
  for (size_t i = (size_t)blockIdx.x * 256 + threadIdx.x; i < L; i += (size_t)gridDim.x * 256) {
    float h = h3[i];
    #pragma unroll
    for (int c = 0; c < 5; c++) acc[c] += h * fcW[(size_t)c * L + i];
  }
  __shared__ float red[4][5];
  #pragma unroll
  for (int msk = 1; msk <= 32; msk <<= 1)
    #pragma unroll
    for (int c = 0; c < 5; c++) acc[c] += __shfl_xor(acc[c], msk);
  int lane = threadIdx.x & 63, wave = threadIdx.x >> 6;
  if (lane == 0)
    #pragma unroll
    for (int c = 0; c < 5; c++) red[wave][c] = acc[c];
  __syncthreads();
  if (threadIdx.x < 5) {
    float s = red[0][threadIdx.x] + red[1][threadIdx.x] + red[2][threadIdx.x] + red[3][threadIdx.x];
    partial[blockIdx.x * 5 + threadIdx.x] = s;
  }
}

__global__ void fc_final_kernel(const float* __restrict__ partial, const float* __restrict__ fcb,
                                float* __restrict__ out) {
  __shared__ float red[4];
  __shared__ float logits[5];
  int tid = threadIdx.x;
  for (int c = 0; c < 5; c++) {
    float a = 0.f;
    for (int b = tid; b < FC_BLOCKS; b += 256) a += partial[b * 5 + c];
    #pragma unroll
    for (int msk = 1; msk <= 32; msk <<= 1) a += __shfl_xor(a, msk);
    if ((tid & 63) == 0) red[tid >> 6] = a;
    __syncthreads();
    if (tid == 0) logits[c] = red[0] + red[1] + red[2] + red[3] + fcb[c];
    __syncthreads();
  }
  if (tid == 0) {
    float mx = logits[0];
    for (int c = 1; c < 5; c++) mx = fmaxf(mx, logits[c]);
    float e[5], s = 0.f;
    for (int c = 0; c < 5; c++) { e[c] = expf(logits[c] - mx); s += e[c]; }
    for (int c = 0; c < 5; c++) out[c] = e[c] / s;
  }
}

// ---------------------------------------------------------------------------
extern "C" void kernel_launch(void* const* d_in, const int* in_sizes, int n_in,
                              void* d_out, int out_size, void* d_ws, size_t ws_size,
                              hipStream_t stream) {
  (void)in_sizes; (void)n_in; (void)out_size; (void)ws_size;
  const float* x   = (const float*)d_in[0];
  const int*   ei  = (const int*)d_in[1];
  const float* W1l = (const float*)d_in[2];
  const float* b1  = (const float*)d_in[3];
  const float* W1r = (const float*)d_in[4];
  const float* W2l = (const float*)d_in[5];
  const float* b2  = (const float*)d_in[6];
  const float* W2r = (const float*)d_in[7];
  const float* W3l = (const float*)d_in[8];
  const float* b3  = (const float*)d_in[9];
  const float* W3r = (const float*)d_in[10];
  const float* fcW = (const float*)d_in[11];
  const float* fcb = (const float*)d_in[12];
  const int* src = ei;
  const int* dst = ei + N_EDGES;

  char* ws = (char*)d_ws;
  size_t off = 0;
  auto alloc = [&](size_t bytes) { void* p = ws + off; off += (bytes + 255) & ~(size_t)255; return p; };
  int*   cnt     = (int*)alloc((size_t)N_NODES * 4);
  int*   row_ptr = (int*)alloc((size_t)(N_NODES + 1) * 4);
  int*   bsum    = (int*)alloc(512);
  float* inv_deg = (float*)alloc((size_t)N_NODES * 4);
  int*   col     = (int*)alloc((size_t)N_EDGES * 4);
  unsigned short* w1b = (unsigned short*)alloc((size_t)256 * 256 * 2);
  unsigned short* w2b = (unsigned short*)alloc((size_t)256 * 256 * 2);
  unsigned short* w3b = (unsigned short*)alloc((size_t)128 * 128 * 2);
  float* partial = (float*)alloc((size_t)FC_BLOCKS * 5 * 4);
  unsigned short* B0 = (unsigned short*)alloc((size_t)N_NODES * 128 * 2);  // xb -> y2r
  unsigned short* B1 = (unsigned short*)alloc((size_t)N_NODES * 128 * 2);  // mean1 -> y2l
  unsigned short* B2 = (unsigned short*)alloc((size_t)N_NODES * 256 * 2);  // h1 -> {y3l, y3r}
  unsigned short* B3 = (unsigned short*)alloc((size_t)N_NODES * 128 * 2);  // h2
  float* B4 = (float*)alloc((size_t)N_NODES * 64 * 4);                      // h3 (fp32 for FC)
  float* out5 = (float*)d_out;

  unsigned short* xb    = B0;
  unsigned short* mean1 = B1;
  unsigned short* h1    = B2;
  unsigned short* y2l   = B1;
  unsigned short* y2r   = B0;
  unsigned short* h2    = B3;
  unsigned short* y3l   = B2;
  unsigned short* y3r   = B2 + (size_t)N_NODES * 64;
  float*          h3f   = B4;

  const int NCH = (N_NODES + 511) / 512;  // 98

  // ---- CSR build ----
  hipMemsetAsync(cnt, 0, (size_t)N_NODES * 4, stream);
  hist_kernel<<<(N_EDGES + 255) / 256, 256, 0, stream>>>(dst, cnt);
  chunk_sum_kernel<<<NCH, 512, 0, stream>>>(cnt, bsum);
  scan_bsum_kernel<<<1, 64, 0, stream>>>(bsum, NCH);
  scan_final_kernel<<<NCH, 512, 0, stream>>>(cnt, bsum, row_ptr, inv_deg);
  hipMemsetAsync(cnt, 0, (size_t)N_NODES * 4, stream);
  fill_csr_kernel<<<(N_EDGES + 255) / 256, 256, 0, stream>>>(src, dst, row_ptr, cnt, col);

  // ---- x -> bf16, pack weights ----
  f2b_kernel<<<(N_NODES * 128 / 4 + 255) / 256, 256, 0, stream>>>(x, xb, N_NODES * 128 / 4);
  pack_kcat_kernel<<<(256 * 256 + 255) / 256, 256, 0, stream>>>(W1l, W1r, w1b, 128, 256);
  pack_jcat_kernel<<<(256 * 256 + 255) / 256, 256, 0, stream>>>(W2l, W2r, w2b, 256, 128);
  pack_jcat_kernel<<<(128 * 128 + 255) / 256, 256, 0, stream>>>(W3l, W3r, w3b, 128, 64);

  const int AGB = N_NODES / 4;            // 12500 (4 waves/block, 1 node/wave)
  const int GB  = (N_NODES + 63) / 64;    // 782

  // ---- Layer 1: aggregate-first (128 -> 256) ----
  agg_mean_bf16<<<AGB, 256, 0, stream>>>(xb, row_ptr, col, inv_deg, mean1);
  mfma_gemm<256, 256, true, true, false><<<GB, 256, 0, stream>>>(mean1, xb, w1b, b1, h1, nullptr);

  // ---- Layer 2: transform-first (256 -> 128) ----
  mfma_gemm<256, 256, false, false, true><<<GB, 256, 0, stream>>>(h1, nullptr, w2b, nullptr, y2l, y2r);
  agg_nr128<<<AGB, 256, 0, stream>>>(y2l, y2r, b2, row_ptr, col, inv_deg, h2);

  // ---- Layer 3: transform-first (128 -> 64) ----
  mfma_gemm<128, 128, false, false, true><<<GB, 256, 0, stream>>>(h2, nullptr, w3b, nullptr, y3l, y3r);
  agg_nr64<<<AGB, 256, 0, stream>>>(y3l, y3r, b3, row_ptr, col, inv_deg, h3f);

  // ---- FC + softmax ----
  fc_partial_kernel<<<FC_BLOCKS, 256, 0, stream>>>(fcW, h3f, partial);
  fc_final_kernel<<<1, 256, 0, stream>>>(partial, fcb, out5);
}

// Round 4
// 254.219 us; speedup vs baseline: 2.0117x; 1.0842x over previous
//
#include <hip/hip_runtime.h>
#include <hip/hip_bf16.h>
#include <math.h>

#define N_NODES 50000
#define N_EDGES 500000
#define FC_BLOCKS 1024

typedef __bf16 bf16x8 __attribute__((ext_vector_type(8)));
typedef float f32x4 __attribute__((ext_vector_type(4)));
typedef unsigned int u32x4 __attribute__((ext_vector_type(4)));

static __device__ __forceinline__ float bf2f_lo(unsigned int v) {
  return __uint_as_float(v << 16);
}
static __device__ __forceinline__ float bf2f_hi(unsigned int v) {
  return __uint_as_float(v & 0xffff0000u);
}
static __device__ __forceinline__ unsigned short f2bf(float f) {
  unsigned int u = __float_as_uint(f);
  return (unsigned short)((u + 0x7fffu + ((u >> 16) & 1u)) >> 16);
}
static __device__ __forceinline__ bf16x8 ld8(const unsigned short* p) {
  u32x4 u = *(const u32x4*)p;
  return __builtin_bit_cast(bf16x8, u);
}

// ---------------------------------------------------------------------------
// CSR build
// ---------------------------------------------------------------------------
__global__ void hist_kernel(const int* __restrict__ dst, int* __restrict__ cnt) {
  int e = blockIdx.x * blockDim.x + threadIdx.x;
  if (e < N_EDGES) atomicAdd(&cnt[dst[e]], 1);
}

__global__ void chunk_sum_kernel(const int* __restrict__ cnt, int* __restrict__ bsum) {
  __shared__ int s[512];
  int i = blockIdx.x * 512 + threadIdx.x;
  s[threadIdx.x] = (i < N_NODES) ? cnt[i] : 0;
  __syncthreads();
  for (int off = 256; off > 0; off >>= 1) {
    if (threadIdx.x < off) s[threadIdx.x] += s[threadIdx.x + off];
    __syncthreads();
  }
  if (threadIdx.x == 0) bsum[blockIdx.x] = s[0];
}

__global__ void scan_bsum_kernel(int* __restrict__ bsum, int n) {
  if (blockIdx.x == 0 && threadIdx.x == 0) {
    int acc = 0;
    for (int i = 0; i < n; i++) { int v = bsum[i]; bsum[i] = acc; acc += v; }
  }
}

__global__ void scan_final_kernel(const int* __restrict__ cnt, const int* __restrict__ bsum,
                                  int* __restrict__ row_ptr, float* __restrict__ inv_deg) {
  __shared__ int s[512];
  int i = blockIdx.x * 512 + threadIdx.x;
  int v = (i < N_NODES) ? cnt[i] : 0;
  s[threadIdx.x] = v;
  __syncthreads();
  for (int off = 1; off < 512; off <<= 1) {
    int t = (threadIdx.x >= off) ? s[threadIdx.x - off] : 0;
    __syncthreads();
    s[threadIdx.x] += t;
    __syncthreads();
  }
  if (i < N_NODES) {
    row_ptr[i + 1] = bsum[blockIdx.x] + s[threadIdx.x];
    if (i == 0) row_ptr[0] = 0;
    inv_deg[i] = 1.0f / fmaxf((float)v, 1.0f);
  }
}

__global__ void fill_csr_kernel(const int* __restrict__ src, const int* __restrict__ dst,
                                const int* __restrict__ row_ptr, int* __restrict__ fill,
                                int* __restrict__ col) {
  int e = blockIdx.x * blockDim.x + threadIdx.x;
  if (e < N_EDGES) {
    int d = dst[e];
    int pos = row_ptr[d] + atomicAdd(&fill[d], 1);
    col[pos] = src[e];
  }
}

// ---------------------------------------------------------------------------
// fp32 -> bf16 convert
// ---------------------------------------------------------------------------
__global__ void f2b_kernel(const float* __restrict__ in, unsigned short* __restrict__ out, int n4) {
  int i = blockIdx.x * 256 + threadIdx.x;
  if (i < n4) {
    float4 v = ((const float4*)in)[i];
    ushort4 o;
    o.x = f2bf(v.x); o.y = f2bf(v.y); o.z = f2bf(v.z); o.w = f2bf(v.w);
    ((ushort4*)out)[i] = o;
  }
}

// ---------------------------------------------------------------------------
// Weight packing: [FO][FI] bf16 row-major
// ---------------------------------------------------------------------------
__global__ void pack_kcat_kernel(const float* __restrict__ Wl, const float* __restrict__ Wr,
                                 unsigned short* __restrict__ Wt, int FIh, int FO) {
  int idx = blockIdx.x * 256 + threadIdx.x;
  int FI = 2 * FIh;
  if (idx < FI * FO) {
    int j = idx / FI, k = idx % FI;
    float v = (k < FIh) ? Wl[j * FIh + k] : Wr[j * FIh + (k - FIh)];
    Wt[idx] = f2bf(v);
  }
}

__global__ void pack_jcat_kernel(const float* __restrict__ Wl, const float* __restrict__ Wr,
                                 unsigned short* __restrict__ Wt, int FI, int FOh) {
  int idx = blockIdx.x * 256 + threadIdx.x;
  if (idx < 2 * FOh * FI) {
    int j = idx / FI, k = idx % FI;
    float v = (j < FOh) ? Wl[j * FI + k] : Wr[(j - FOh) * FI + k];
    Wt[idx] = f2bf(v);
  }
}

// ---------------------------------------------------------------------------
// Aggregation: 1 wave per node, 16-lane groups gather different edges.
// ---------------------------------------------------------------------------
#define ACC8(v)                                          \
  do {                                                   \
    a[0] += bf2f_lo((v)[0]); a[1] += bf2f_hi((v)[0]);    \
    a[2] += bf2f_lo((v)[1]); a[3] += bf2f_hi((v)[1]);    \
    a[4] += bf2f_lo((v)[2]); a[5] += bf2f_hi((v)[2]);    \
    a[6] += bf2f_lo((v)[3]); a[7] += bf2f_hi((v)[3]);    \
  } while (0)

__global__ void agg_mean_bf16(const unsigned short* __restrict__ xb, const int* __restrict__ rp,
                              const int* __restrict__ cl, const float* __restrict__ idg,
                              unsigned short* __restrict__ out) {
  int node = blockIdx.x * 4 + (threadIdx.x >> 6);
  int lane = threadIdx.x & 63;
  int g = lane >> 4, l = lane & 15;
  int beg = rp[node], end = rp[node + 1];
  float a[8] = {0.f, 0.f, 0.f, 0.f, 0.f, 0.f, 0.f, 0.f};
  for (int e0 = beg; e0 < end; e0 += 8) {
    int e1 = e0 + g, e2 = e0 + 4 + g;
    if (e1 < end) {
      u32x4 v = *(const u32x4*)(xb + (size_t)cl[e1] * 128 + l * 8);
      ACC8(v);
    }
    if (e2 < end) {
      u32x4 v = *(const u32x4*)(xb + (size_t)cl[e2] * 128 + l * 8);
      ACC8(v);
    }
  }
  #pragma unroll
  for (int i = 0; i < 8; i++) {
    a[i] += __shfl_xor(a[i], 16);
    a[i] += __shfl_xor(a[i], 32);
  }
  if (g == 0) {
    float s = idg[node];
    u32x4 o;
    #pragma unroll
    for (int i = 0; i < 4; i++)
      o[i] = (unsigned int)f2bf(a[2 * i] * s) | ((unsigned int)f2bf(a[2 * i + 1] * s) << 16);
    *(u32x4*)(out + (size_t)node * 128 + l * 8) = o;
  }
}

// h = relu(l2norm(mean_gather(yl) + bias + yr_row)), F=128, bf16 out
__global__ void agg_nr128(const unsigned short* __restrict__ yl, const unsigned short* __restrict__ yr,
                          const float* __restrict__ bias, const int* __restrict__ rp,
                          const int* __restrict__ cl, const float* __restrict__ idg,
                          unsigned short* __restrict__ outb) {
  int node = blockIdx.x * 4 + (threadIdx.x >> 6);
  int lane = threadIdx.x & 63;
  int g = lane >> 4, l = lane & 15;
  int beg = rp[node], end = rp[node + 1];
  float a[8] = {0.f, 0.f, 0.f, 0.f, 0.f, 0.f, 0.f, 0.f};
  for (int e0 = beg; e0 < end; e0 += 8) {
    int e1 = e0 + g, e2 = e0 + 4 + g;
    if (e1 < end) {
      u32x4 v = *(const u32x4*)(yl + (size_t)cl[e1] * 128 + l * 8);
      ACC8(v);
    }
    if (e2 < end) {
      u32x4 v = *(const u32x4*)(yl + (size_t)cl[e2] * 128 + l * 8);
      ACC8(v);
    }
  }
  #pragma unroll
  for (int i = 0; i < 8; i++) {
    a[i] += __shfl_xor(a[i], 16);
    a[i] += __shfl_xor(a[i], 32);
  }
  float s = idg[node];
  u32x4 r = *(const u32x4*)(yr + (size_t)node * 128 + l * 8);
  float v[8];
  v[0] = a[0] * s + bias[l * 8 + 0] + bf2f_lo(r[0]);
  v[1] = a[1] * s + bias[l * 8 + 1] + bf2f_hi(r[0]);
  v[2] = a[2] * s + bias[l * 8 + 2] + bf2f_lo(r[1]);
  v[3] = a[3] * s + bias[l * 8 + 3] + bf2f_hi(r[1]);
  v[4] = a[4] * s + bias[l * 8 + 4] + bf2f_lo(r[2]);
  v[5] = a[5] * s + bias[l * 8 + 5] + bf2f_hi(r[2]);
  v[6] = a[6] * s + bias[l * 8 + 6] + bf2f_lo(r[3]);
  v[7] = a[7] * s + bias[l * 8 + 7] + bf2f_hi(r[3]);
  float p = 0.f;
  #pragma unroll
  for (int i = 0; i < 8; i++) p += v[i] * v[i];
  #pragma unroll
  for (int msk = 1; msk <= 8; msk <<= 1) p += __shfl_xor(p, msk);
  float sc = 1.0f / fmaxf(sqrtf(p), 1e-12f);
  if (g == 0) {
    u32x4 o;
    #pragma unroll
    for (int i = 0; i < 4; i++) {
      float w0 = fmaxf(v[2 * i] * sc, 0.f);
      float w1 = fmaxf(v[2 * i + 1] * sc, 0.f);
      o[i] = (unsigned int)f2bf(w0) | ((unsigned int)f2bf(w1) << 16);
    }
    *(u32x4*)(outb + (size_t)node * 128 + l * 8) = o;
  }
}

// h = relu(l2norm(mean_gather(yl) + bias + yr_row)), F=64, fp32 out
__global__ void agg_nr64(const unsigned short* __restrict__ yl, const unsigned short* __restrict__ yr,
                         const float* __restrict__ bias, const int* __restrict__ rp,
                         const int* __restrict__ cl, const float* __restrict__ idg,
                         float* __restrict__ outf) {
  int node = blockIdx.x * 4 + (threadIdx.x >> 6);
  int lane = threadIdx.x & 63;
  int g = lane >> 3, l = lane & 7;
  int beg = rp[node], end = rp[node + 1];
  float a[8] = {0.f, 0.f, 0.f, 0.f, 0.f, 0.f, 0.f, 0.f};
  for (int e0 = beg; e0 < end; e0 += 16) {
    int e1 = e0 + g, e2 = e0 + 8 + g;
    if (e1 < end) {
      u32x4 v = *(const u32x4*)(yl + (size_t)cl[e1] * 64 + l * 8);
      ACC8(v);
    }
    if (e2 < end) {
      u32x4 v = *(const u32x4*)(yl + (size_t)cl[e2] * 64 + l * 8);
      ACC8(v);
    }
  }
  #pragma unroll
  for (int i = 0; i < 8; i++) {
    a[i] += __shfl_xor(a[i], 8);
    a[i] += __shfl_xor(a[i], 16);
    a[i] += __shfl_xor(a[i], 32);
  }
  float s = idg[node];
  u32x4 r = *(const u32x4*)(yr + (size_t)node * 64 + l * 8);
  float v[8];
  v[0] = a[0] * s + bias[l * 8 + 0] + bf2f_lo(r[0]);
  v[1] = a[1] * s + bias[l * 8 + 1] + bf2f_hi(r[0]);
  v[2] = a[2] * s + bias[l * 8 + 2] + bf2f_lo(r[1]);
  v[3] = a[3] * s + bias[l * 8 + 3] + bf2f_hi(r[1]);
  v[4] = a[4] * s + bias[l * 8 + 4] + bf2f_lo(r[2]);
  v[5] = a[5] * s + bias[l * 8 + 5] + bf2f_hi(r[2]);
  v[6] = a[6] * s + bias[l * 8 + 6] + bf2f_lo(r[3]);
  v[7] = a[7] * s + bias[l * 8 + 7] + bf2f_hi(r[3]);
  float p = 0.f;
  #pragma unroll
  for (int i = 0; i < 8; i++) p += v[i] * v[i];
  #pragma unroll
  for (int msk = 1; msk <= 4; msk <<= 1) p += __shfl_xor(p, msk);
  float sc = 1.0f / fmaxf(sqrtf(p), 1e-12f);
  if (g == 0) {
    f32x4 o0, o1;
    #pragma unroll
    for (int i = 0; i < 4; i++) o0[i] = fmaxf(v[i] * sc, 0.f);
    #pragma unroll
    for (int i = 0; i < 4; i++) o1[i] = fmaxf(v[4 + i] * sc, 0.f);
    *(f32x4*)(outf + (size_t)node * 64 + l * 8) = o0;
    *(f32x4*)(outf + (size_t)node * 64 + l * 8 + 4) = o1;
  }
}

// ---------------------------------------------------------------------------
// MFMA GEMM v2: out[N,FO] = A[N,FI](bf16) @ W[FO][FI](bf16)^T
// Block 256 thr (4 waves), tile 64 rows x FO cols; wave owns all 64 rows x
// FO/4 cols. A-tile staged in LDS (XOR-swizzled, conflict-free ds_read_b128);
// W frags double-buffered in registers (L2-resident). MFMA called as
// mfma(Wfrag, Afrag) so each lane's 4 acc regs = 4 consecutive OUTPUT COLS
// -> packed 8B stores. POST: +bias, L2-norm over FO, relu.
// ---------------------------------------------------------------------------
template<int FI, int FO, bool ASPLIT, bool POST, bool OSPLIT>
__launch_bounds__(256)
__global__ void mfma_gemm(const unsigned short* __restrict__ A1, const unsigned short* __restrict__ A2,
                          const unsigned short* __restrict__ W, const float* __restrict__ bias,
                          unsigned short* __restrict__ outA, unsigned short* __restrict__ outB) {
  constexpr int ROWB = FI * 2;          // LDS bytes per row
  constexpr int JF = FO / 64;           // 16-col frags per wave
  __shared__ unsigned char As[64 * ROWB];
  __shared__ float sums[64][5];
  const int tid = threadIdx.x;
  const int wave = tid >> 6, lane = tid & 63;
  const int l15 = lane & 15, kg = lane >> 4;
  const int row0 = blockIdx.x * 64;
  const int wj = wave * (FO / 4);       // wave's output-col base

  // ---- stage A tile into LDS (coalesced global read, swizzled LDS write) ----
  #pragma unroll
  for (int i = 0; i < (64 * ROWB) / 4096; i++) {
    int boff = i * 4096 + tid * 16;
    int row = boff / ROWB;
    int colb = boff % ROWB;
    int grow = row0 + row; if (grow >= N_NODES) grow = N_NODES - 1;
    u32x4 v;
    if (ASPLIT) {
      if (colb < ROWB / 2) v = *(const u32x4*)((const char*)A1 + (size_t)grow * (ROWB / 2) + colb);
      else                 v = *(const u32x4*)((const char*)A2 + (size_t)grow * (ROWB / 2) + colb - ROWB / 2);
    } else {
      v = *(const u32x4*)((const char*)A1 + (size_t)grow * ROWB + colb);
    }
    *(u32x4*)(&As[row * ROWB + (colb ^ ((row & 7) << 4))]) = v;
  }

  f32x4 acc[JF][4];
  #pragma unroll
  for (int jf = 0; jf < JF; jf++)
    #pragma unroll
    for (int mf = 0; mf < 4; mf++) acc[jf][mf] = (f32x4){0.f, 0.f, 0.f, 0.f};

  // preload W frags for k0 = 0
  const unsigned short* Wp = W + (size_t)(wj + l15) * FI + kg * 8;
  bf16x8 wc[JF], wn[JF];
  #pragma unroll
  for (int jf = 0; jf < JF; jf++) wc[jf] = ld8(Wp + (size_t)jf * 16 * FI);

  __syncthreads();

  #pragma unroll
  for (int k0 = 0; k0 < FI; k0 += 32) {
    if (k0 + 32 < FI) {
      #pragma unroll
      for (int jf = 0; jf < JF; jf++) wn[jf] = ld8(Wp + (size_t)jf * 16 * FI + k0 + 32);
    }
    bf16x8 af[4];
    int colb = (k0 + kg * 8) * 2;
    #pragma unroll
    for (int mf = 0; mf < 4; mf++) {
      int row = mf * 16 + l15;
      af[mf] = ld8((const unsigned short*)&As[row * ROWB + (colb ^ ((row & 7) << 4))]);
    }
    #pragma unroll
    for (int jf = 0; jf < JF; jf++)
      #pragma unroll
      for (int mf = 0; mf < 4; mf++)
        acc[jf][mf] = __builtin_amdgcn_mfma_f32_16x16x32_bf16(wc[jf], af[mf], acc[jf][mf], 0, 0, 0);
    if (k0 + 32 < FI) {
      #pragma unroll
      for (int jf = 0; jf < JF; jf++) wc[jf] = wn[jf];
    }
  }

  if (POST) {
    float bj[JF][4];
    #pragma unroll
    for (int jf = 0; jf < JF; jf++)
      #pragma unroll
      for (int r = 0; r < 4; r++) bj[jf][r] = bias[wj + jf * 16 + kg * 4 + r];
    float p[4] = {0.f, 0.f, 0.f, 0.f};
    #pragma unroll
    for (int jf = 0; jf < JF; jf++)
      #pragma unroll
      for (int mf = 0; mf < 4; mf++)
        #pragma unroll
        for (int r = 0; r < 4; r++) {
          float v = acc[jf][mf][r] + bj[jf][r];
          acc[jf][mf][r] = v;
          p[mf] += v * v;
        }
    #pragma unroll
    for (int mf = 0; mf < 4; mf++) {
      p[mf] += __shfl_xor(p[mf], 16);
      p[mf] += __shfl_xor(p[mf], 32);
    }
    if (kg == 0) {
      #pragma unroll
      for (int mf = 0; mf < 4; mf++) sums[mf * 16 + l15][wave] = p[mf];
    }
    __syncthreads();
    #pragma unroll
    for (int mf = 0; mf < 4; mf++) {
      int rl = mf * 16 + l15;
      float tot = sums[rl][0] + sums[rl][1] + sums[rl][2] + sums[rl][3];
      float sc = 1.0f / fmaxf(sqrtf(tot), 1e-12f);
      #pragma unroll
      for (int jf = 0; jf < JF; jf++)
        #pragma unroll
        for (int r = 0; r < 4; r++) acc[jf][mf][r] = fmaxf(acc[jf][mf][r] * sc, 0.f);
    }
  }

  unsigned short* ob = outA;
  int cb = wj;
  constexpr int OSTR = OSPLIT ? FO / 2 : FO;
  if (OSPLIT && wj >= FO / 2) { ob = outB; cb = wj - FO / 2; }
  #pragma unroll
  for (int mf = 0; mf < 4; mf++) {
    int m = row0 + mf * 16 + l15;
    if (m < N_NODES) {
      #pragma unroll
      for (int jf = 0; jf < JF; jf++) {
        ushort4 o;
        o.x = f2bf(acc[jf][mf][0]);
        o.y = f2bf(acc[jf][mf][1]);
        o.z = f2bf(acc[jf][mf][2]);
        o.w = f2bf(acc[jf][mf][3]);
        *(ushort4*)&ob[(size_t)m * OSTR + cb + jf * 16 + kg * 4] = o;
      }
    }
  }
}

// ---------------------------------------------------------------------------
// FC: logits = fcW @ h3.flat + fcb; softmax
// ---------------------------------------------------------------------------
__global__ void fc_partial_kernel(const float* __restrict__ fcW, const float* __restrict__ h3,
                                  float* __restrict__ partial) {
  const size_t L = (size_t)N_NODES * 64;
  float acc[5] = {0.f, 0.f, 0.f, 0.f, 0.f};
  for (size_t i = (size_t)blockIdx.x * 256 + threadIdx.x; i < L; i += (size_t)gridDim.x * 256) {
    float h = h3[i];
    #pragma unroll
    for (int c = 0; c < 5; c++) acc[c] += h * fcW[(size_t)c * L + i];
  }
  __shared__ float red[4][5];
  #pragma unroll
  for (int msk = 1; msk <= 32; msk <<= 1)
    #pragma unroll
    for (int c = 0; c < 5; c++) acc[c] += __shfl_xor(acc[c], msk);
  int lane = threadIdx.x & 63, wave = threadIdx.x >> 6;
  if (lane == 0)
    #pragma unroll
    for (int c = 0; c < 5; c++) red[wave][c] = acc[c];
  __syncthreads();
  if (threadIdx.x < 5) {
    float s = red[0][threadIdx.x] + red[1][threadIdx.x] + red[2][threadIdx.x] + red[3][threadIdx.x];
    partial[blockIdx.x * 5 + threadIdx.x] = s;
  }
}

__global__ void fc_final_kernel(const float* __restrict__ partial, const float* __restrict__ fcb,
                                float* __restrict__ out) {
  __shared__ float red[4];
  __shared__ float logits[5];
  int tid = threadIdx.x;
  for (int c = 0; c < 5; c++) {
    float a = 0.f;
    for (int b = tid; b < FC_BLOCKS; b += 256) a += partial[b * 5 + c];
    #pragma unroll
    for (int msk = 1; msk <= 32; msk <<= 1) a += __shfl_xor(a, msk);
    if ((tid & 63) == 0) red[tid >> 6] = a;
    __syncthreads();
    if (tid == 0) logits[c] = red[0] + red[1] + red[2] + red[3] + fcb[c];
    __syncthreads();
  }
  if (tid == 0) {
    float mx = logits[0];
    for (int c = 1; c < 5; c++) mx = fmaxf(mx, logits[c]);
    float e[5], s = 0.f;
    for (int c = 0; c < 5; c++) { e[c] = expf(logits[c] - mx); s += e[c]; }
    for (int c = 0; c < 5; c++) out[c] = e[c] / s;
  }
}

// ---------------------------------------------------------------------------
extern "C" void kernel_launch(void* const* d_in, const int* in_sizes, int n_in,
                              void* d_out, int out_size, void* d_ws, size_t ws_size,
                              hipStream_t stream) {
  (void)in_sizes; (void)n_in; (void)out_size; (void)ws_size;
  const float* x   = (const float*)d_in[0];
  const int*   ei  = (const int*)d_in[1];
  const float* W1l = (const float*)d_in[2];
  const float* b1  = (const float*)d_in[3];
  const float* W1r = (const float*)d_in[4];
  const float* W2l = (const float*)d_in[5];
  const float* b2  = (const float*)d_in[6];
  const float* W2r = (const float*)d_in[7];
  const float* W3l = (const float*)d_in[8];
  const float* b3  = (const float*)d_in[9];
  const float* W3r = (const float*)d_in[10];
  const float* fcW = (const float*)d_in[11];
  const float* fcb = (const float*)d_in[12];
  const int* src = ei;
  const int* dst = ei + N_EDGES;

  char* ws = (char*)d_ws;
  size_t off = 0;
  auto alloc = [&](size_t bytes) { void* p = ws + off; off += (bytes + 255) & ~(size_t)255; return p; };
  int*   cnt     = (int*)alloc((size_t)N_NODES * 4);
  int*   row_ptr = (int*)alloc((size_t)(N_NODES + 1) * 4);
  int*   bsum    = (int*)alloc(512);
  float* inv_deg = (float*)alloc((size_t)N_NODES * 4);
  int*   col     = (int*)alloc((size_t)N_EDGES * 4);
  unsigned short* w1b = (unsigned short*)alloc((size_t)256 * 256 * 2);
  unsigned short* w2b = (unsigned short*)alloc((size_t)256 * 256 * 2);
  unsigned short* w3b = (unsigned short*)alloc((size_t)128 * 128 * 2);
  float* partial = (float*)alloc((size_t)FC_BLOCKS * 5 * 4);
  unsigned short* B0 = (unsigned short*)alloc((size_t)N_NODES * 128 * 2);  // xb -> y2r
  unsigned short* B1 = (unsigned short*)alloc((size_t)N_NODES * 128 * 2);  // mean1 -> y2l
  unsigned short* B2 = (unsigned short*)alloc((size_t)N_NODES * 256 * 2);  // h1 -> {y3l, y3r}
  unsigned short* B3 = (unsigned short*)alloc((size_t)N_NODES * 128 * 2);  // h2
  float* B4 = (float*)alloc((size_t)N_NODES * 64 * 4);                      // h3 (fp32 for FC)
  float* out5 = (float*)d_out;

  unsigned short* xb    = B0;
  unsigned short* mean1 = B1;
  unsigned short* h1    = B2;
  unsigned short* y2l   = B1;
  unsigned short* y2r   = B0;
  unsigned short* h2    = B3;
  unsigned short* y3l   = B2;
  unsigned short* y3r   = B2 + (size_t)N_NODES * 64;
  float*          h3f   = B4;

  const int NCH = (N_NODES + 511) / 512;  // 98

  // ---- CSR build ----
  hipMemsetAsync(cnt, 0, (size_t)N_NODES * 4, stream);
  hist_kernel<<<(N_EDGES + 255) / 256, 256, 0, stream>>>(dst, cnt);
  chunk_sum_kernel<<<NCH, 512, 0, stream>>>(cnt, bsum);
  scan_bsum_kernel<<<1, 64, 0, stream>>>(bsum, NCH);
  scan_final_kernel<<<NCH, 512, 0, stream>>>(cnt, bsum, row_ptr, inv_deg);
  hipMemsetAsync(cnt, 0, (size_t)N_NODES * 4, stream);
  fill_csr_kernel<<<(N_EDGES + 255) / 256, 256, 0, stream>>>(src, dst, row_ptr, cnt, col);

  // ---- x -> bf16, pack weights ----
  f2b_kernel<<<(N_NODES * 128 / 4 + 255) / 256, 256, 0, stream>>>(x, xb, N_NODES * 128 / 4);
  pack_kcat_kernel<<<(256 * 256 + 255) / 256, 256, 0, stream>>>(W1l, W1r, w1b, 128, 256);
  pack_jcat_kernel<<<(256 * 256 + 255) / 256, 256, 0, stream>>>(W2l, W2r, w2b, 256, 128);
  pack_jcat_kernel<<<(128 * 128 + 255) / 256, 256, 0, stream>>>(W3l, W3r, w3b, 128, 64);

  const int AGB = N_NODES / 4;            // 12500 (4 waves/block, 1 node/wave)
  const int GB  = (N_NODES + 63) / 64;    // 782

  // ---- Layer 1: aggregate-first (128 -> 256) ----
  agg_mean_bf16<<<AGB, 256, 0, stream>>>(xb, row_ptr, col, inv_deg, mean1);
  mfma_gemm<256, 256, true, true, false><<<GB, 256, 0, stream>>>(mean1, xb, w1b, b1, h1, nullptr);

  // ---- Layer 2: transform-first (256 -> 128) ----
  mfma_gemm<256, 256, false, false, true><<<GB, 256, 0, stream>>>(h1, nullptr, w2b, nullptr, y2l, y2r);
  agg_nr128<<<AGB, 256, 0, stream>>>(y2l, y2r, b2, row_ptr, col, inv_deg, h2);

  // ---- Layer 3: transform-first (128 -> 64) ----
  mfma_gemm<128, 128, false, false, true><<<GB, 256, 0, stream>>>(h2, nullptr, w3b, nullptr, y3l, y3r);
  agg_nr64<<<AGB, 256, 0, stream>>>(y3l, y3r, b3, row_ptr, col, inv_deg, h3f);

  // ---- FC + softmax ----
  fc_partial_kernel<<<FC_BLOCKS, 256, 0, stream>>>(fcW, h3f, partial);
  fc_final_kernel<<<1, 256, 0, stream>>>(partial, fcb, out5);
}